// Round 4
// baseline (709.632 us; speedup 1.0000x reference)
//
#include <hip/hip_runtime.h>
#include <hip/hip_bf16.h>

// ============ CSR build: histogram -> scan -> fill ============

__global__ void k_hist(const int* __restrict__ dst, int* __restrict__ counts, int E) {
    int e = blockIdx.x * blockDim.x + threadIdx.x;
    int stride = gridDim.x * blockDim.x;
    for (; e < E; e += stride) atomicAdd(&counts[dst[e]], 1);
}

__global__ void k_dinv(const int* __restrict__ counts, float* __restrict__ dinv, int N) {
    int i = blockIdx.x * blockDim.x + threadIdx.x;
    if (i < N) dinv[i] = rsqrtf((float)(counts[i] + 1));   // +1 self loop
}

// exclusive scan, 3-phase
__global__ void k_scan1(const int* __restrict__ counts, int* __restrict__ rowptr,
                        int* __restrict__ bsum, int N) {
    __shared__ int tmp[256];
    int i = blockIdx.x * 256 + threadIdx.x;
    int v = (i < N) ? counts[i] : 0;
    tmp[threadIdx.x] = v;
    __syncthreads();
    for (int off = 1; off < 256; off <<= 1) {
        int t = (threadIdx.x >= off) ? tmp[threadIdx.x - off] : 0;
        __syncthreads();
        tmp[threadIdx.x] += t;
        __syncthreads();
    }
    if (i < N) rowptr[i] = tmp[threadIdx.x] - v;
    if (threadIdx.x == 255) bsum[blockIdx.x] = tmp[255];
}

__global__ void k_scan2(int* bsum, int nb) {
    __shared__ int tmp[512];
    int t = threadIdx.x;
    int v = (t < nb) ? bsum[t] : 0;
    tmp[t] = v;
    __syncthreads();
    for (int off = 1; off < 512; off <<= 1) {
        int u = (t >= off) ? tmp[t - off] : 0;
        __syncthreads();
        tmp[t] += u;
        __syncthreads();
    }
    if (t < nb) bsum[t] = tmp[t] - v;
}

__global__ void k_scan3(int* __restrict__ rowptr, const int* __restrict__ bsum, int N) {
    int i = blockIdx.x * 256 + threadIdx.x;
    if (i < N) rowptr[i] += bsum[blockIdx.x];
}

// fill src indices sorted by dst; cursor pre-initialized to rowptr copy
__global__ void k_fill(const int* __restrict__ ei, int* __restrict__ cursor,
                       int* __restrict__ ssrc, int E) {
    int e = blockIdx.x * blockDim.x + threadIdx.x;
    int stride = gridDim.x * blockDim.x;
    const int* srcp = ei;
    const int* dstp = ei + E;
    for (; e < E; e += stride) {
        int s = srcp[e];
        int d = dstp[e];
        int p = atomicAdd(&cursor[d], 1);
        ssrc[p] = s;
    }
}

// ============ embed GEMM: h = x @ We^T ([N,128] @ [128,64]^T) ============

__global__ __launch_bounds__(256) void k_embed(const float* __restrict__ x,
                                               const float* __restrict__ We,
                                               float* __restrict__ h, int N) {
    __shared__ float Ws[64 * 129];
    __shared__ float xs[32 * 128];
    int tid = threadIdx.x;

#pragma unroll
    for (int i = 0; i < 32; ++i) {
        int m = tid + i * 256;
        Ws[(m >> 7) * 129 + (m & 127)] = We[m];
    }
    int base = blockIdx.x * 32;
    const float4* x4 = (const float4*)(x + (size_t)base * 128);
#pragma unroll
    for (int i = 0; i < 4; ++i) {
        int m = tid + i * 256;
        ((float4*)xs)[m] = x4[m];
    }
    __syncthreads();

    int f = tid & 63, g = tid >> 6;
    float acc[8] = {0, 0, 0, 0, 0, 0, 0, 0};
#pragma unroll 4
    for (int k = 0; k < 128; k += 4) {
        float w0 = Ws[f * 129 + k + 0];
        float w1 = Ws[f * 129 + k + 1];
        float w2 = Ws[f * 129 + k + 2];
        float w3 = Ws[f * 129 + k + 3];
#pragma unroll
        for (int j = 0; j < 8; ++j) {
            const float4 xv = *(const float4*)&xs[(g * 8 + j) * 128 + k];
            acc[j] = fmaf(xv.x, w0, acc[j]);
            acc[j] = fmaf(xv.y, w1, acc[j]);
            acc[j] = fmaf(xv.z, w2, acc[j]);
            acc[j] = fmaf(xv.w, w3, acc[j]);
        }
    }
#pragma unroll
    for (int j = 0; j < 8; ++j) {
        int r = base + g * 8 + j;
        h[(size_t)r * 64 + f] = acc[j];
    }
}

// ============ GCN layer GEMM: hws = (act(hin) @ Wg^T) * dinv ============

__global__ __launch_bounds__(256) void k_gcn(const float* __restrict__ hin,
                                             const float* __restrict__ Wg,
                                             const float* __restrict__ bias_prev, int act,
                                             const float* __restrict__ dinv,
                                             float* __restrict__ hws, int N) {
    __shared__ float Ws[64 * 65];
    __shared__ float xs[32 * 64];
    int tid = threadIdx.x;

#pragma unroll
    for (int i = 0; i < 16; ++i) {
        int m = tid + i * 256;
        Ws[(m >> 6) * 65 + (m & 63)] = Wg[m];
    }
    int base = blockIdx.x * 32;
    const float4* hin4 = (const float4*)(hin + (size_t)base * 64);
#pragma unroll
    for (int i = 0; i < 2; ++i) {
        int m = tid + i * 256;
        float4 v = hin4[m];
        if (act) {
            int kf = (m & 15) * 4;
            v.x = fmaxf(v.x + bias_prev[kf + 0], 0.f);
            v.y = fmaxf(v.y + bias_prev[kf + 1], 0.f);
            v.z = fmaxf(v.z + bias_prev[kf + 2], 0.f);
            v.w = fmaxf(v.w + bias_prev[kf + 3], 0.f);
        }
        ((float4*)xs)[m] = v;
    }
    __syncthreads();

    int f = tid & 63, g = tid >> 6;
    float acc[8] = {0, 0, 0, 0, 0, 0, 0, 0};
#pragma unroll 4
    for (int k = 0; k < 64; k += 4) {
        float w0 = Ws[f * 65 + k + 0];
        float w1 = Ws[f * 65 + k + 1];
        float w2 = Ws[f * 65 + k + 2];
        float w3 = Ws[f * 65 + k + 3];
#pragma unroll
        for (int j = 0; j < 8; ++j) {
            const float4 xv = *(const float4*)&xs[(g * 8 + j) * 64 + k];
            acc[j] = fmaf(xv.x, w0, acc[j]);
            acc[j] = fmaf(xv.y, w1, acc[j]);
            acc[j] = fmaf(xv.z, w2, acc[j]);
            acc[j] = fmaf(xv.w, w3, acc[j]);
        }
    }
#pragma unroll
    for (int j = 0; j < 8; ++j) {
        int r = base + g * 8 + j;
        hws[(size_t)r * 64 + f] = acc[j] * dinv[r];
    }
}

// ============ CSR gather-aggregate: one wave per dst node, 8-way MLP ============
// out[d] = dinv[d] * (hws[d] + sum_{e in row d} hws[src_e])

__global__ __launch_bounds__(256) void k_agg(const int* __restrict__ rowptr,
                                             const int* __restrict__ counts,
                                             const int* __restrict__ ssrc,
                                             const float* __restrict__ dinv,
                                             const float* __restrict__ hws,
                                             float* __restrict__ out, int N) {
    int lane = threadIdx.x & 63;
    int d = blockIdx.x * 4 + (threadIdx.x >> 6);
    if (d >= N) return;

    float a0 = hws[((size_t)d << 6) + lane];   // self loop
    float a1 = 0.f, a2 = 0.f, a3 = 0.f, a4 = 0.f, a5 = 0.f, a6 = 0.f, a7 = 0.f;

    int beg = rowptr[d];
    int cnt = counts[d];
    for (int base = 0; base < cnt; base += 64) {
        int m = min(64, cnt - base);
        int s = (lane < m) ? ssrc[beg + base + lane] : 0;
        int j = 0;
        for (; j + 7 < m; j += 8) {
            int s0 = __shfl(s, j + 0);
            int s1 = __shfl(s, j + 1);
            int s2 = __shfl(s, j + 2);
            int s3 = __shfl(s, j + 3);
            int s4 = __shfl(s, j + 4);
            int s5 = __shfl(s, j + 5);
            int s6 = __shfl(s, j + 6);
            int s7 = __shfl(s, j + 7);
            float h0 = hws[((size_t)s0 << 6) + lane];
            float h1 = hws[((size_t)s1 << 6) + lane];
            float h2 = hws[((size_t)s2 << 6) + lane];
            float h3 = hws[((size_t)s3 << 6) + lane];
            float h4 = hws[((size_t)s4 << 6) + lane];
            float h5 = hws[((size_t)s5 << 6) + lane];
            float h6 = hws[((size_t)s6 << 6) + lane];
            float h7 = hws[((size_t)s7 << 6) + lane];
            a0 += h0; a1 += h1; a2 += h2; a3 += h3;
            a4 += h4; a5 += h5; a6 += h6; a7 += h7;
        }
        for (; j < m; ++j) {
            int sj = __shfl(s, j);
            a0 += hws[((size_t)sj << 6) + lane];
        }
    }
    float t = ((a0 + a1) + (a2 + a3)) + ((a4 + a5) + (a6 + a7));
    out[((size_t)d << 6) + lane] = dinv[d] * t;
}

// ============ centroid squared norms ============

__global__ void k_c2(const float* __restrict__ C, float* __restrict__ c2) {
    int k = threadIdx.x;
    if (k < 100) {
        float s = 0.f;
        for (int d = 0; d < 64; ++d) { float v = C[k * 64 + d]; s = fmaf(v, v, s); }
        c2[k] = s;
    }
}

// ============ centroid distances + pooling: thread = node, quadratic form ============

__global__ __launch_bounds__(256) void k_cent(const float* __restrict__ hin,
                                              const float* __restrict__ b2,
                                              const float* __restrict__ C,
                                              const float* __restrict__ c2g,
                                              float* __restrict__ pooled, int N) {
    __shared__ float pooled_s[128];
    int tid = threadIdx.x;
    if (tid < 128) pooled_s[tid] = 0.f;
    __syncthreads();

    int n = blockIdx.x * 256 + tid;
    bool valid = n < N;

    float h[64];
    float h2 = 0.f;
    {
        const float4* h4 = (const float4*)(hin + ((size_t)(valid ? n : 0) << 6));
#pragma unroll
        for (int i = 0; i < 16; ++i) {
            float4 v = h4[i];
            v.x = fmaxf(v.x + b2[4 * i + 0], 0.f);
            v.y = fmaxf(v.y + b2[4 * i + 1], 0.f);
            v.z = fmaxf(v.z + b2[4 * i + 2], 0.f);
            v.w = fmaxf(v.w + b2[4 * i + 3], 0.f);
            h[4 * i + 0] = v.x; h[4 * i + 1] = v.y;
            h[4 * i + 2] = v.z; h[4 * i + 3] = v.w;
            h2 = fmaf(v.x, v.x, h2); h2 = fmaf(v.y, v.y, h2);
            h2 = fmaf(v.z, v.z, h2); h2 = fmaf(v.w, v.w, h2);
        }
    }

    for (int k = 0; k < 100; ++k) {
        const float* crow = C + k * 64;   // wave-uniform -> scalar loads
        float acc = 0.f;
#pragma unroll
        for (int d = 0; d < 64; ++d) acc = fmaf(h[d], crow[d], acc);
        float d2 = fmaxf(h2 + c2g[k] - 2.f * acc, 0.f);
        float dist = valid ? sqrtf(d2 + 1e-12f) : 0.f;
        // wave butterfly reduce
#pragma unroll
        for (int off = 32; off > 0; off >>= 1) dist += __shfl_xor(dist, off);
        if ((tid & 63) == 0) atomicAdd(&pooled_s[k], dist);
    }
    __syncthreads();
    if (tid < 100) atomicAdd(&pooled[tid], pooled_s[tid]);
}

// ============ output head ============

__global__ void k_out(const float* __restrict__ pooled,
                      const float* __restrict__ Wout,
                      const float* __restrict__ bout,
                      float* __restrict__ out, float invN) {
    int t = threadIdx.x;
    if (t < 10) {
        float s = 0.f;
        for (int k = 0; k < 100; ++k) s += pooled[k] * Wout[t * 100 + k];
        out[t] = s * invN + bout[t];
    }
}

// ============ launcher ============

extern "C" void kernel_launch(void* const* d_in, const int* in_sizes, int n_in,
                              void* d_out, int out_size, void* d_ws, size_t ws_size,
                              hipStream_t stream) {
    const float* x    = (const float*)d_in[0];
    const int*   ei   = (const int*)d_in[1];
    const float* We   = (const float*)d_in[2];
    const float* Wg   = (const float*)d_in[3];
    const float* bg   = (const float*)d_in[4];
    const float* C    = (const float*)d_in[5];
    const float* Wout = (const float*)d_in[6];
    const float* bout = (const float*)d_in[7];
    float*       out  = (float*)d_out;

    const int N = in_sizes[0] / 128;    // 100000
    const int E = in_sizes[1] / 2;      // 1600000
    const int NB = (N + 255) / 256;     // scan blocks (391)

    char* ws = (char*)d_ws;
    size_t off = 0;
    auto alloc = [&](size_t bytes) { void* p = ws + off; off += (bytes + 511) & ~(size_t)511; return p; };
    float* dinv   = (float*)alloc((size_t)N * 4);
    int*   counts = (int*)  alloc((size_t)N * 4);
    int*   cursor = (int*)  alloc((size_t)N * 4);
    int*   rowptr = (int*)  alloc((size_t)N * 4);
    int*   bsum   = (int*)  alloc((size_t)NB * 4);
    int*   ssrc   = (int*)  alloc((size_t)E * 4);
    float* hA     = (float*)alloc((size_t)N * 64 * 4);
    float* hB     = (float*)alloc((size_t)N * 64 * 4);
    float* c2     = (float*)alloc(512);
    float* pooled = (float*)alloc(512);

    hipMemsetAsync(counts, 0, (size_t)N * 4, stream);
    hipMemsetAsync(pooled, 0, 512, stream);

    // CSR build
    k_hist<<<4096, 256, 0, stream>>>(ei + E, counts, E);
    k_dinv<<<NB, 256, 0, stream>>>(counts, dinv, N);
    k_scan1<<<NB, 256, 0, stream>>>(counts, rowptr, bsum, N);
    k_scan2<<<1, 512, 0, stream>>>(bsum, NB);
    k_scan3<<<NB, 256, 0, stream>>>(rowptr, bsum, N);
    hipMemcpyAsync(cursor, rowptr, (size_t)N * 4, hipMemcpyDeviceToDevice, stream);
    k_fill<<<4096, 256, 0, stream>>>(ei, cursor, ssrc, E);
    k_c2<<<1, 128, 0, stream>>>(C, c2);

    // embed
    k_embed<<<N / 32, 256, 0, stream>>>(x, We, hA, N);

    // 3 GCN layers: gemm (hA->hB, scaled by dinv), aggregate (hB->hA)
    for (int l = 0; l < 3; ++l) {
        const float* bias_prev = (l == 0) ? bg : (bg + (l - 1) * 64);
        int act = (l == 0) ? 0 : 1;
        k_gcn<<<N / 32, 256, 0, stream>>>(hA, Wg + (size_t)l * 64 * 64, bias_prev, act,
                                          dinv, hB, N);
        k_agg<<<(N + 3) / 4, 256, 0, stream>>>(rowptr, counts, ssrc, dinv, hB, hA, N);
    }

    // centroid distances + pooling (applies relu + b_gcn[2])
    k_cent<<<NB, 256, 0, stream>>>(hA, bg + 2 * 64, C, c2, pooled, N);

    // head
    k_out<<<1, 64, 0, stream>>>(pooled, Wout, bout, out, 1.0f / (float)N);
}

// Round 5
// 643.666 us; speedup vs baseline: 1.1025x; 1.1025x over previous
//
#include <hip/hip_runtime.h>
#include <hip/hip_bf16.h>

// ============ CSR build: histogram -> scan -> fill ============

__global__ void k_hist(const int* __restrict__ dst, int* __restrict__ counts, int E) {
    int e = blockIdx.x * blockDim.x + threadIdx.x;
    int stride = gridDim.x * blockDim.x;
    for (; e < E; e += stride) atomicAdd(&counts[dst[e]], 1);
}

__global__ void k_dinv(const int* __restrict__ counts, float* __restrict__ dinv, int N) {
    int i = blockIdx.x * blockDim.x + threadIdx.x;
    if (i < N) dinv[i] = rsqrtf((float)(counts[i] + 1));   // +1 self loop
}

// exclusive scan, 3-phase
__global__ void k_scan1(const int* __restrict__ counts, int* __restrict__ rowptr,
                        int* __restrict__ bsum, int N) {
    __shared__ int tmp[256];
    int i = blockIdx.x * 256 + threadIdx.x;
    int v = (i < N) ? counts[i] : 0;
    tmp[threadIdx.x] = v;
    __syncthreads();
    for (int off = 1; off < 256; off <<= 1) {
        int t = (threadIdx.x >= off) ? tmp[threadIdx.x - off] : 0;
        __syncthreads();
        tmp[threadIdx.x] += t;
        __syncthreads();
    }
    if (i < N) rowptr[i] = tmp[threadIdx.x] - v;
    if (threadIdx.x == 255) bsum[blockIdx.x] = tmp[255];
}

__global__ void k_scan2(int* bsum, int nb) {
    __shared__ int tmp[512];
    int t = threadIdx.x;
    int v = (t < nb) ? bsum[t] : 0;
    tmp[t] = v;
    __syncthreads();
    for (int off = 1; off < 512; off <<= 1) {
        int u = (t >= off) ? tmp[t - off] : 0;
        __syncthreads();
        tmp[t] += u;
        __syncthreads();
    }
    if (t < nb) bsum[t] = tmp[t] - v;
}

// writes final rowptr AND initializes cursor (replaces d2d memcpy)
__global__ void k_scan3(int* __restrict__ rowptr, int* __restrict__ cursor,
                        const int* __restrict__ bsum, int N) {
    int i = blockIdx.x * 256 + threadIdx.x;
    if (i < N) {
        int v = rowptr[i] + bsum[blockIdx.x];
        rowptr[i] = v;
        cursor[i] = v;
    }
}

// batched fill: 8 edges/thread, all 8 returning atomics in flight together
__global__ __launch_bounds__(256) void k_fill(const int* __restrict__ ei,
                                              int* __restrict__ cursor,
                                              int* __restrict__ ssrc, int E) {
    int t = blockIdx.x * 256 + threadIdx.x;
    int nt = gridDim.x * 256;
    int s[8], d[8], p[8];
#pragma unroll
    for (int i = 0; i < 8; ++i) {
        int e = t + i * nt;
        if (e < E) { s[i] = ei[e]; d[i] = ei[E + e]; }
    }
#pragma unroll
    for (int i = 0; i < 8; ++i) {
        int e = t + i * nt;
        if (e < E) p[i] = atomicAdd(&cursor[d[i]], 1);
    }
#pragma unroll
    for (int i = 0; i < 8; ++i) {
        int e = t + i * nt;
        if (e < E) ssrc[p[i]] = s[i];
    }
}

// ============ embed GEMM: h = x @ We^T ([N,128] @ [128,64]^T) ============

__global__ __launch_bounds__(256) void k_embed(const float* __restrict__ x,
                                               const float* __restrict__ We,
                                               float* __restrict__ h, int N) {
    __shared__ float Ws[64 * 129];
    __shared__ float xs[32 * 128];
    int tid = threadIdx.x;

#pragma unroll
    for (int i = 0; i < 32; ++i) {
        int m = tid + i * 256;
        Ws[(m >> 7) * 129 + (m & 127)] = We[m];
    }
    int base = blockIdx.x * 32;
    const float4* x4 = (const float4*)(x + (size_t)base * 128);
#pragma unroll
    for (int i = 0; i < 4; ++i) {
        int m = tid + i * 256;
        ((float4*)xs)[m] = x4[m];
    }
    __syncthreads();

    int f = tid & 63, g = tid >> 6;
    float acc[8] = {0, 0, 0, 0, 0, 0, 0, 0};
#pragma unroll 4
    for (int k = 0; k < 128; k += 4) {
        float w0 = Ws[f * 129 + k + 0];
        float w1 = Ws[f * 129 + k + 1];
        float w2 = Ws[f * 129 + k + 2];
        float w3 = Ws[f * 129 + k + 3];
#pragma unroll
        for (int j = 0; j < 8; ++j) {
            const float4 xv = *(const float4*)&xs[(g * 8 + j) * 128 + k];
            acc[j] = fmaf(xv.x, w0, acc[j]);
            acc[j] = fmaf(xv.y, w1, acc[j]);
            acc[j] = fmaf(xv.z, w2, acc[j]);
            acc[j] = fmaf(xv.w, w3, acc[j]);
        }
    }
#pragma unroll
    for (int j = 0; j < 8; ++j) {
        int r = base + g * 8 + j;
        h[(size_t)r * 64 + f] = acc[j];
    }
}

// ============ GCN layer GEMM: hws = (act(hin) @ Wg^T) * dinv ============

__global__ __launch_bounds__(256) void k_gcn(const float* __restrict__ hin,
                                             const float* __restrict__ Wg,
                                             const float* __restrict__ bias_prev, int act,
                                             const float* __restrict__ dinv,
                                             float* __restrict__ hws, int N) {
    __shared__ float Ws[64 * 65];
    __shared__ float xs[32 * 64];
    int tid = threadIdx.x;

#pragma unroll
    for (int i = 0; i < 16; ++i) {
        int m = tid + i * 256;
        Ws[(m >> 6) * 65 + (m & 63)] = Wg[m];
    }
    int base = blockIdx.x * 32;
    const float4* hin4 = (const float4*)(hin + (size_t)base * 64);
#pragma unroll
    for (int i = 0; i < 2; ++i) {
        int m = tid + i * 256;
        float4 v = hin4[m];
        if (act) {
            int kf = (m & 15) * 4;
            v.x = fmaxf(v.x + bias_prev[kf + 0], 0.f);
            v.y = fmaxf(v.y + bias_prev[kf + 1], 0.f);
            v.z = fmaxf(v.z + bias_prev[kf + 2], 0.f);
            v.w = fmaxf(v.w + bias_prev[kf + 3], 0.f);
        }
        ((float4*)xs)[m] = v;
    }
    __syncthreads();

    int f = tid & 63, g = tid >> 6;
    float acc[8] = {0, 0, 0, 0, 0, 0, 0, 0};
#pragma unroll 4
    for (int k = 0; k < 64; k += 4) {
        float w0 = Ws[f * 65 + k + 0];
        float w1 = Ws[f * 65 + k + 1];
        float w2 = Ws[f * 65 + k + 2];
        float w3 = Ws[f * 65 + k + 3];
#pragma unroll
        for (int j = 0; j < 8; ++j) {
            const float4 xv = *(const float4*)&xs[(g * 8 + j) * 64 + k];
            acc[j] = fmaf(xv.x, w0, acc[j]);
            acc[j] = fmaf(xv.y, w1, acc[j]);
            acc[j] = fmaf(xv.z, w2, acc[j]);
            acc[j] = fmaf(xv.w, w3, acc[j]);
        }
    }
#pragma unroll
    for (int j = 0; j < 8; ++j) {
        int r = base + g * 8 + j;
        hws[(size_t)r * 64 + f] = acc[j] * dinv[r];
    }
}

// ============ CSR gather-aggregate: one wave per dst, float4 lanes ============
// out[d] = dinv[d] * (hws[d] + sum_{e in row d} hws[src_e])
// lane = (sub, q): sub = lane>>4 picks 1 of 4 edges/group, q = lane&15 picks float4 of row.

__global__ __launch_bounds__(256) void k_agg(const int* __restrict__ rowptr,
                                             const int* __restrict__ counts,
                                             const int* __restrict__ ssrc,
                                             const float* __restrict__ dinv,
                                             const float* __restrict__ hws,
                                             float* __restrict__ out, int N) {
    int lane = threadIdx.x & 63;
    int d = blockIdx.x * 4 + (threadIdx.x >> 6);
    if (d >= N) return;
    int q = lane & 15;
    int sub = lane >> 4;
    const float4* hws4 = (const float4*)hws;

    float4 acc = make_float4(0.f, 0.f, 0.f, 0.f);
    if (sub == 0) acc = hws4[((size_t)d << 4) + q];   // self loop, counted once

    int beg = rowptr[d];
    int cnt = counts[d];
    for (int base = 0; base < cnt; base += 64) {
        int m = min(64, cnt - base);
        int s = (lane < m) ? ssrc[beg + base + lane] : 0;
        int full = m >> 2;
        int g = 0;
        for (; g + 3 < full; g += 4) {
            int i0 = __shfl(s, (g + 0) * 4 + sub);
            int i1 = __shfl(s, (g + 1) * 4 + sub);
            int i2 = __shfl(s, (g + 2) * 4 + sub);
            int i3 = __shfl(s, (g + 3) * 4 + sub);
            float4 v0 = hws4[((size_t)i0 << 4) + q];
            float4 v1 = hws4[((size_t)i1 << 4) + q];
            float4 v2 = hws4[((size_t)i2 << 4) + q];
            float4 v3 = hws4[((size_t)i3 << 4) + q];
            acc.x += v0.x + v1.x + v2.x + v3.x;
            acc.y += v0.y + v1.y + v2.y + v3.y;
            acc.z += v0.z + v1.z + v2.z + v3.z;
            acc.w += v0.w + v1.w + v2.w + v3.w;
        }
        for (; g < full; ++g) {
            int i0 = __shfl(s, g * 4 + sub);
            float4 v0 = hws4[((size_t)i0 << 4) + q];
            acc.x += v0.x; acc.y += v0.y; acc.z += v0.z; acc.w += v0.w;
        }
        int t = m & 3;
        if (t) {
            int idx = full * 4 + sub;          // < 64 always; s defined on all lanes
            int i0 = __shfl(s, idx);
            if (sub < t) {
                float4 v0 = hws4[((size_t)i0 << 4) + q];
                acc.x += v0.x; acc.y += v0.y; acc.z += v0.z; acc.w += v0.w;
            }
        }
    }

    // combine across sub (lanes 16 apart hold partial sums of same q)
    acc.x += __shfl_xor(acc.x, 16); acc.y += __shfl_xor(acc.y, 16);
    acc.z += __shfl_xor(acc.z, 16); acc.w += __shfl_xor(acc.w, 16);
    acc.x += __shfl_xor(acc.x, 32); acc.y += __shfl_xor(acc.y, 32);
    acc.z += __shfl_xor(acc.z, 32); acc.w += __shfl_xor(acc.w, 32);

    if (sub == 0) {
        float dd = dinv[d];
        ((float4*)out)[((size_t)d << 4) + q] =
            make_float4(dd * acc.x, dd * acc.y, dd * acc.z, dd * acc.w);
    }
}

// ============ centroid squared norms ============

__global__ void k_c2(const float* __restrict__ C, float* __restrict__ c2) {
    int k = threadIdx.x;
    if (k < 100) {
        float s = 0.f;
        for (int d = 0; d < 64; ++d) { float v = C[k * 64 + d]; s = fmaf(v, v, s); }
        c2[k] = s;
    }
}

// ============ centroid distances + pooling: thread = node, quadratic form ============

__global__ __launch_bounds__(256) void k_cent(const float* __restrict__ hin,
                                              const float* __restrict__ b2,
                                              const float* __restrict__ C,
                                              const float* __restrict__ c2g,
                                              float* __restrict__ pooled, int N) {
    __shared__ float pooled_s[128];
    int tid = threadIdx.x;
    if (tid < 128) pooled_s[tid] = 0.f;
    __syncthreads();

    int n = blockIdx.x * 256 + tid;
    bool valid = n < N;

    float h[64];
    float h2 = 0.f;
    {
        const float4* h4 = (const float4*)(hin + ((size_t)(valid ? n : 0) << 6));
#pragma unroll
        for (int i = 0; i < 16; ++i) {
            float4 v = h4[i];
            v.x = fmaxf(v.x + b2[4 * i + 0], 0.f);
            v.y = fmaxf(v.y + b2[4 * i + 1], 0.f);
            v.z = fmaxf(v.z + b2[4 * i + 2], 0.f);
            v.w = fmaxf(v.w + b2[4 * i + 3], 0.f);
            h[4 * i + 0] = v.x; h[4 * i + 1] = v.y;
            h[4 * i + 2] = v.z; h[4 * i + 3] = v.w;
            h2 = fmaf(v.x, v.x, h2); h2 = fmaf(v.y, v.y, h2);
            h2 = fmaf(v.z, v.z, h2); h2 = fmaf(v.w, v.w, h2);
        }
    }

    for (int k = 0; k < 100; ++k) {
        const float* crow = C + k * 64;   // wave-uniform -> scalar loads
        float acc = 0.f;
#pragma unroll
        for (int d = 0; d < 64; ++d) acc = fmaf(h[d], crow[d], acc);
        float d2 = fmaxf(h2 + c2g[k] - 2.f * acc, 0.f);
        float dist = valid ? sqrtf(d2 + 1e-12f) : 0.f;
#pragma unroll
        for (int off = 32; off > 0; off >>= 1) dist += __shfl_xor(dist, off);
        if ((tid & 63) == 0) atomicAdd(&pooled_s[k], dist);
    }
    __syncthreads();
    if (tid < 100) atomicAdd(&pooled[tid], pooled_s[tid]);
}

// ============ output head ============

__global__ void k_out(const float* __restrict__ pooled,
                      const float* __restrict__ Wout,
                      const float* __restrict__ bout,
                      float* __restrict__ out, float invN) {
    int t = threadIdx.x;
    if (t < 10) {
        float s = 0.f;
        for (int k = 0; k < 100; ++k) s += pooled[k] * Wout[t * 100 + k];
        out[t] = s * invN + bout[t];
    }
}

// ============ launcher ============

extern "C" void kernel_launch(void* const* d_in, const int* in_sizes, int n_in,
                              void* d_out, int out_size, void* d_ws, size_t ws_size,
                              hipStream_t stream) {
    const float* x    = (const float*)d_in[0];
    const int*   ei   = (const int*)d_in[1];
    const float* We   = (const float*)d_in[2];
    const float* Wg   = (const float*)d_in[3];
    const float* bg   = (const float*)d_in[4];
    const float* C    = (const float*)d_in[5];
    const float* Wout = (const float*)d_in[6];
    const float* bout = (const float*)d_in[7];
    float*       out  = (float*)d_out;

    const int N = in_sizes[0] / 128;    // 100000
    const int E = in_sizes[1] / 2;      // 1600000
    const int NB = (N + 255) / 256;     // scan blocks (391)

    char* ws = (char*)d_ws;
    size_t off = 0;
    auto alloc = [&](size_t bytes) { void* p = ws + off; off += (bytes + 511) & ~(size_t)511; return p; };
    float* dinv   = (float*)alloc((size_t)N * 4);
    int*   counts = (int*)  alloc((size_t)N * 4);
    int*   cursor = (int*)  alloc((size_t)N * 4);
    int*   rowptr = (int*)  alloc((size_t)N * 4);
    int*   bsum   = (int*)  alloc((size_t)NB * 4);
    int*   ssrc   = (int*)  alloc((size_t)E * 4);
    float* hA     = (float*)alloc((size_t)N * 64 * 4);
    float* hB     = (float*)alloc((size_t)N * 64 * 4);
    float* c2     = (float*)alloc(512);
    float* pooled = (float*)alloc(512);

    hipMemsetAsync(counts, 0, (size_t)N * 4, stream);
    hipMemsetAsync(pooled, 0, 512, stream);

    // CSR build
    k_hist<<<4096, 256, 0, stream>>>(ei + E, counts, E);
    k_dinv<<<NB, 256, 0, stream>>>(counts, dinv, N);
    k_scan1<<<NB, 256, 0, stream>>>(counts, rowptr, bsum, N);
    k_scan2<<<1, 512, 0, stream>>>(bsum, NB);
    k_scan3<<<NB, 256, 0, stream>>>(rowptr, cursor, bsum, N);
    k_fill<<<(E + 256 * 8 - 1) / (256 * 8), 256, 0, stream>>>(ei, cursor, ssrc, E);
    k_c2<<<1, 128, 0, stream>>>(C, c2);

    // embed
    k_embed<<<N / 32, 256, 0, stream>>>(x, We, hA, N);

    // 3 GCN layers: gemm (hA->hB, scaled by dinv), aggregate (hB->hA)
    for (int l = 0; l < 3; ++l) {
        const float* bias_prev = (l == 0) ? bg : (bg + (l - 1) * 64);
        int act = (l == 0) ? 0 : 1;
        k_gcn<<<N / 32, 256, 0, stream>>>(hA, Wg + (size_t)l * 64 * 64, bias_prev, act,
                                          dinv, hB, N);
        k_agg<<<(N + 3) / 4, 256, 0, stream>>>(rowptr, counts, ssrc, dinv, hB, hA, N);
    }

    // centroid distances + pooling (applies relu + b_gcn[2])
    k_cent<<<NB, 256, 0, stream>>>(hA, bg + 2 * 64, C, c2, pooled, N);

    // head
    k_out<<<1, 64, 0, stream>>>(pooled, Wout, bout, out, 1.0f / (float)N);
}

// Round 6
// 600.637 us; speedup vs baseline: 1.1815x; 1.0716x over previous
//
#include <hip/hip_runtime.h>
#include <hip/hip_bf16.h>

typedef unsigned int uint32;
typedef unsigned short ushort16;

// float -> bf16 with round-to-nearest-even
static __device__ __forceinline__ ushort16 f2bf(float f) {
    uint32 u = __float_as_uint(f);
    u += 0x7fffu + ((u >> 16) & 1u);
    return (ushort16)(u >> 16);
}

// ============ CSR build: histogram -> scan -> fill ============

__global__ void k_hist(const int* __restrict__ dst, int* __restrict__ counts, int E) {
    int e = blockIdx.x * blockDim.x + threadIdx.x;
    int stride = gridDim.x * blockDim.x;
    for (; e < E; e += stride) atomicAdd(&counts[dst[e]], 1);
}

__global__ void k_dinv(const int* __restrict__ counts, float* __restrict__ dinv, int N) {
    int i = blockIdx.x * blockDim.x + threadIdx.x;
    if (i < N) dinv[i] = rsqrtf((float)(counts[i] + 1));   // +1 self loop
}

// exclusive scan, 3-phase
__global__ void k_scan1(const int* __restrict__ counts, int* __restrict__ rowptr,
                        int* __restrict__ bsum, int N) {
    __shared__ int tmp[256];
    int i = blockIdx.x * 256 + threadIdx.x;
    int v = (i < N) ? counts[i] : 0;
    tmp[threadIdx.x] = v;
    __syncthreads();
    for (int off = 1; off < 256; off <<= 1) {
        int t = (threadIdx.x >= off) ? tmp[threadIdx.x - off] : 0;
        __syncthreads();
        tmp[threadIdx.x] += t;
        __syncthreads();
    }
    if (i < N) rowptr[i] = tmp[threadIdx.x] - v;
    if (threadIdx.x == 255) bsum[blockIdx.x] = tmp[255];
}

__global__ void k_scan2(int* bsum, int nb) {
    __shared__ int tmp[512];
    int t = threadIdx.x;
    int v = (t < nb) ? bsum[t] : 0;
    tmp[t] = v;
    __syncthreads();
    for (int off = 1; off < 512; off <<= 1) {
        int u = (t >= off) ? tmp[t - off] : 0;
        __syncthreads();
        tmp[t] += u;
        __syncthreads();
    }
    if (t < nb) bsum[t] = tmp[t] - v;
}

__global__ void k_scan3(int* __restrict__ rowptr, int* __restrict__ cursor,
                        const int* __restrict__ bsum, int N) {
    int i = blockIdx.x * 256 + threadIdx.x;
    if (i < N) {
        int v = rowptr[i] + bsum[blockIdx.x];
        rowptr[i] = v;
        cursor[i] = v;
    }
}

// batched fill: 4 edges/thread (grid ~1563 blocks -> ~76% occupancy), atomics pipelined
__global__ __launch_bounds__(256) void k_fill(const int* __restrict__ ei,
                                              int* __restrict__ cursor,
                                              int* __restrict__ ssrc, int E) {
    int t = blockIdx.x * 256 + threadIdx.x;
    int nt = gridDim.x * 256;
    int s[4], d[4], p[4];
#pragma unroll
    for (int i = 0; i < 4; ++i) {
        int e = t + i * nt;
        if (e < E) { s[i] = ei[e]; d[i] = ei[E + e]; }
    }
#pragma unroll
    for (int i = 0; i < 4; ++i) {
        int e = t + i * nt;
        if (e < E) p[i] = atomicAdd(&cursor[d[i]], 1);
    }
#pragma unroll
    for (int i = 0; i < 4; ++i) {
        int e = t + i * nt;
        if (e < E) ssrc[p[i]] = s[i];
    }
}

// ============ embed GEMM: h = x @ We^T ([N,128] @ [128,64]^T) ============

__global__ __launch_bounds__(256) void k_embed(const float* __restrict__ x,
                                               const float* __restrict__ We,
                                               float* __restrict__ h, int N) {
    __shared__ float Ws[64 * 129];
    __shared__ float xs[32 * 128];
    int tid = threadIdx.x;

#pragma unroll
    for (int i = 0; i < 32; ++i) {
        int m = tid + i * 256;
        Ws[(m >> 7) * 129 + (m & 127)] = We[m];
    }
    int base = blockIdx.x * 32;
    const float4* x4 = (const float4*)(x + (size_t)base * 128);
#pragma unroll
    for (int i = 0; i < 4; ++i) {
        int m = tid + i * 256;
        ((float4*)xs)[m] = x4[m];
    }
    __syncthreads();

    int f = tid & 63, g = tid >> 6;
    float acc[8] = {0, 0, 0, 0, 0, 0, 0, 0};
#pragma unroll 4
    for (int k = 0; k < 128; k += 4) {
        float w0 = Ws[f * 129 + k + 0];
        float w1 = Ws[f * 129 + k + 1];
        float w2 = Ws[f * 129 + k + 2];
        float w3 = Ws[f * 129 + k + 3];
#pragma unroll
        for (int j = 0; j < 8; ++j) {
            const float4 xv = *(const float4*)&xs[(g * 8 + j) * 128 + k];
            acc[j] = fmaf(xv.x, w0, acc[j]);
            acc[j] = fmaf(xv.y, w1, acc[j]);
            acc[j] = fmaf(xv.z, w2, acc[j]);
            acc[j] = fmaf(xv.w, w3, acc[j]);
        }
    }
#pragma unroll
    for (int j = 0; j < 8; ++j) {
        int r = base + g * 8 + j;
        h[(size_t)r * 64 + f] = acc[j];
    }
}

// ============ GCN layer GEMM: hws = bf16((act(hin) @ Wg^T) * dinv) ============

__global__ __launch_bounds__(256) void k_gcn(const float* __restrict__ hin,
                                             const float* __restrict__ Wg,
                                             const float* __restrict__ bias_prev, int act,
                                             const float* __restrict__ dinv,
                                             ushort16* __restrict__ hwsb, int N) {
    __shared__ float Ws[64 * 65];
    __shared__ float xs[32 * 64];
    int tid = threadIdx.x;

#pragma unroll
    for (int i = 0; i < 16; ++i) {
        int m = tid + i * 256;
        Ws[(m >> 6) * 65 + (m & 63)] = Wg[m];
    }
    int base = blockIdx.x * 32;
    const float4* hin4 = (const float4*)(hin + (size_t)base * 64);
#pragma unroll
    for (int i = 0; i < 2; ++i) {
        int m = tid + i * 256;
        float4 v = hin4[m];
        if (act) {
            int kf = (m & 15) * 4;
            v.x = fmaxf(v.x + bias_prev[kf + 0], 0.f);
            v.y = fmaxf(v.y + bias_prev[kf + 1], 0.f);
            v.z = fmaxf(v.z + bias_prev[kf + 2], 0.f);
            v.w = fmaxf(v.w + bias_prev[kf + 3], 0.f);
        }
        ((float4*)xs)[m] = v;
    }
    __syncthreads();

    int f = tid & 63, g = tid >> 6;
    float acc[8] = {0, 0, 0, 0, 0, 0, 0, 0};
#pragma unroll 4
    for (int k = 0; k < 64; k += 4) {
        float w0 = Ws[f * 65 + k + 0];
        float w1 = Ws[f * 65 + k + 1];
        float w2 = Ws[f * 65 + k + 2];
        float w3 = Ws[f * 65 + k + 3];
#pragma unroll
        for (int j = 0; j < 8; ++j) {
            const float4 xv = *(const float4*)&xs[(g * 8 + j) * 64 + k];
            acc[j] = fmaf(xv.x, w0, acc[j]);
            acc[j] = fmaf(xv.y, w1, acc[j]);
            acc[j] = fmaf(xv.z, w2, acc[j]);
            acc[j] = fmaf(xv.w, w3, acc[j]);
        }
    }
#pragma unroll
    for (int j = 0; j < 8; ++j) {
        int r = base + g * 8 + j;
        hwsb[(size_t)r * 64 + f] = f2bf(acc[j] * dinv[r]);
    }
}

// ============ CSR gather-aggregate: bf16 rows, one wave per dst ============
// out[d] = dinv[d] * (hws[d] + sum_{e in row d} hws[src_e])
// lane = (sub, q): sub = lane>>5 picks 1 of 2 edges per load group,
// q = lane&31 picks a packed uint (2 bf16 feats) of the 128-B row.

__global__ __launch_bounds__(256) void k_agg(const int* __restrict__ rowptr,
                                             const int* __restrict__ counts,
                                             const int* __restrict__ ssrc,
                                             const float* __restrict__ dinv,
                                             const uint32* __restrict__ hwsu,
                                             float* __restrict__ out, int N) {
    int lane = threadIdx.x & 63;
    int d = blockIdx.x * 4 + (threadIdx.x >> 6);
    if (d >= N) return;
    int q = lane & 31;
    int sub = lane >> 5;

    float ax = 0.f, ay = 0.f;
    if (sub == 0) {   // self loop counted once
        uint32 v = hwsu[((size_t)d << 5) + q];
        ax = __uint_as_float(v << 16);
        ay = __uint_as_float(v & 0xffff0000u);
    }

    int beg = rowptr[d];
    int cnt = counts[d];
    for (int base = 0; base < cnt; base += 64) {
        int m = min(64, cnt - base);
        int s = (lane < m) ? ssrc[beg + base + lane] : 0;
        int full2 = m >> 1;    // pairs of edges
        int g = 0;
        for (; g + 3 < full2; g += 4) {
            int i0 = __shfl(s, (g + 0) * 2 + sub);
            int i1 = __shfl(s, (g + 1) * 2 + sub);
            int i2 = __shfl(s, (g + 2) * 2 + sub);
            int i3 = __shfl(s, (g + 3) * 2 + sub);
            uint32 v0 = hwsu[((size_t)i0 << 5) + q];
            uint32 v1 = hwsu[((size_t)i1 << 5) + q];
            uint32 v2 = hwsu[((size_t)i2 << 5) + q];
            uint32 v3 = hwsu[((size_t)i3 << 5) + q];
            ax += __uint_as_float(v0 << 16); ay += __uint_as_float(v0 & 0xffff0000u);
            ax += __uint_as_float(v1 << 16); ay += __uint_as_float(v1 & 0xffff0000u);
            ax += __uint_as_float(v2 << 16); ay += __uint_as_float(v2 & 0xffff0000u);
            ax += __uint_as_float(v3 << 16); ay += __uint_as_float(v3 & 0xffff0000u);
        }
        for (; g < full2; ++g) {
            int i0 = __shfl(s, g * 2 + sub);
            uint32 v0 = hwsu[((size_t)i0 << 5) + q];
            ax += __uint_as_float(v0 << 16); ay += __uint_as_float(v0 & 0xffff0000u);
        }
        if (m & 1) {
            int i0 = __shfl(s, m - 1);
            if (sub == 0) {
                uint32 v0 = hwsu[((size_t)i0 << 5) + q];
                ax += __uint_as_float(v0 << 16); ay += __uint_as_float(v0 & 0xffff0000u);
            }
        }
    }

    // combine the two sub halves (lanes 32 apart hold same q)
    ax += __shfl_xor(ax, 32);
    ay += __shfl_xor(ay, 32);

    if (sub == 0) {
        float dd = dinv[d];
        ((float2*)out)[((size_t)d << 5) + q] = make_float2(dd * ax, dd * ay);
    }
}

// ============ centroid squared norms ============

__global__ void k_c2(const float* __restrict__ C, float* __restrict__ c2) {
    int k = threadIdx.x;
    if (k < 100) {
        float s = 0.f;
        for (int d = 0; d < 64; ++d) { float v = C[k * 64 + d]; s = fmaf(v, v, s); }
        c2[k] = s;
    }
}

// ============ centroid distances + pooling: thread = node, quadratic form ============

__global__ __launch_bounds__(256) void k_cent(const float* __restrict__ hin,
                                              const float* __restrict__ b2,
                                              const float* __restrict__ C,
                                              const float* __restrict__ c2g,
                                              float* __restrict__ pooled, int N) {
    __shared__ float pooled_s[128];
    int tid = threadIdx.x;
    if (tid < 128) pooled_s[tid] = 0.f;
    __syncthreads();

    int n = blockIdx.x * 256 + tid;
    bool valid = n < N;

    float h[64];
    float h2 = 0.f;
    {
        const float4* h4 = (const float4*)(hin + ((size_t)(valid ? n : 0) << 6));
#pragma unroll
        for (int i = 0; i < 16; ++i) {
            float4 v = h4[i];
            v.x = fmaxf(v.x + b2[4 * i + 0], 0.f);
            v.y = fmaxf(v.y + b2[4 * i + 1], 0.f);
            v.z = fmaxf(v.z + b2[4 * i + 2], 0.f);
            v.w = fmaxf(v.w + b2[4 * i + 3], 0.f);
            h[4 * i + 0] = v.x; h[4 * i + 1] = v.y;
            h[4 * i + 2] = v.z; h[4 * i + 3] = v.w;
            h2 = fmaf(v.x, v.x, h2); h2 = fmaf(v.y, v.y, h2);
            h2 = fmaf(v.z, v.z, h2); h2 = fmaf(v.w, v.w, h2);
        }
    }

    for (int k = 0; k < 100; ++k) {
        const float* crow = C + k * 64;   // wave-uniform -> scalar loads
        float acc = 0.f;
#pragma unroll
        for (int d = 0; d < 64; ++d) acc = fmaf(h[d], crow[d], acc);
        float d2 = fmaxf(h2 + c2g[k] - 2.f * acc, 0.f);
        float dist = valid ? sqrtf(d2 + 1e-12f) : 0.f;
#pragma unroll
        for (int off = 32; off > 0; off >>= 1) dist += __shfl_xor(dist, off);
        if ((tid & 63) == 0) atomicAdd(&pooled_s[k], dist);
    }
    __syncthreads();
    if (tid < 100) atomicAdd(&pooled[tid], pooled_s[tid]);
}

// ============ output head ============

__global__ void k_out(const float* __restrict__ pooled,
                      const float* __restrict__ Wout,
                      const float* __restrict__ bout,
                      float* __restrict__ out, float invN) {
    int t = threadIdx.x;
    if (t < 10) {
        float s = 0.f;
        for (int k = 0; k < 100; ++k) s += pooled[k] * Wout[t * 100 + k];
        out[t] = s * invN + bout[t];
    }
}

// ============ launcher ============

extern "C" void kernel_launch(void* const* d_in, const int* in_sizes, int n_in,
                              void* d_out, int out_size, void* d_ws, size_t ws_size,
                              hipStream_t stream) {
    const float* x    = (const float*)d_in[0];
    const int*   ei   = (const int*)d_in[1];
    const float* We   = (const float*)d_in[2];
    const float* Wg   = (const float*)d_in[3];
    const float* bg   = (const float*)d_in[4];
    const float* C    = (const float*)d_in[5];
    const float* Wout = (const float*)d_in[6];
    const float* bout = (const float*)d_in[7];
    float*       out  = (float*)d_out;

    const int N = in_sizes[0] / 128;    // 100000
    const int E = in_sizes[1] / 2;      // 1600000
    const int NB = (N + 255) / 256;     // scan blocks (391)

    char* ws = (char*)d_ws;
    size_t off = 0;
    auto alloc = [&](size_t bytes) { void* p = ws + off; off += (bytes + 511) & ~(size_t)511; return p; };
    float*    dinv   = (float*)alloc((size_t)N * 4);
    int*      counts = (int*)  alloc((size_t)N * 4);
    int*      cursor = (int*)  alloc((size_t)N * 4);
    int*      rowptr = (int*)  alloc((size_t)N * 4);
    int*      bsum   = (int*)  alloc((size_t)NB * 4);
    int*      ssrc   = (int*)  alloc((size_t)E * 4);
    float*    hA     = (float*)alloc((size_t)N * 64 * 4);
    ushort16* hB     = (ushort16*)alloc((size_t)N * 64 * 2);   // bf16 hws
    float*    c2     = (float*)alloc(512);
    float*    pooled = (float*)alloc(512);

    hipMemsetAsync(counts, 0, (size_t)N * 4, stream);
    hipMemsetAsync(pooled, 0, 512, stream);

    // CSR build
    k_hist<<<4096, 256, 0, stream>>>(ei + E, counts, E);
    k_dinv<<<NB, 256, 0, stream>>>(counts, dinv, N);
    k_scan1<<<NB, 256, 0, stream>>>(counts, rowptr, bsum, N);
    k_scan2<<<1, 512, 0, stream>>>(bsum, NB);
    k_scan3<<<NB, 256, 0, stream>>>(rowptr, cursor, bsum, N);
    k_fill<<<(E + 256 * 4 - 1) / (256 * 4), 256, 0, stream>>>(ei, cursor, ssrc, E);
    k_c2<<<1, 128, 0, stream>>>(C, c2);

    // embed
    k_embed<<<N / 32, 256, 0, stream>>>(x, We, hA, N);

    // 3 GCN layers: gemm (hA -> hB bf16, scaled by dinv), aggregate (hB -> hA fp32)
    for (int l = 0; l < 3; ++l) {
        const float* bias_prev = (l == 0) ? bg : (bg + (l - 1) * 64);
        int act = (l == 0) ? 0 : 1;
        k_gcn<<<N / 32, 256, 0, stream>>>(hA, Wg + (size_t)l * 64 * 64, bias_prev, act,
                                          dinv, hB, N);
        k_agg<<<(N + 3) / 4, 256, 0, stream>>>(rowptr, counts, ssrc, dinv,
                                               (const uint32*)hB, hA, N);
    }

    // centroid distances + pooling (applies relu + b_gcn[2])
    k_cent<<<NB, 256, 0, stream>>>(hA, bg + 2 * 64, C, c2, pooled, N);

    // head
    k_out<<<1, 64, 0, stream>>>(pooled, Wout, bout, out, 1.0f / (float)N);
}